// Round 4
// baseline (777.604 us; speedup 1.0000x reference)
//
#include <hip/hip_runtime.h>
#include <hip/hip_bf16.h>
#include <stdint.h>

typedef __hip_bfloat16 bf16;
typedef __attribute__((ext_vector_type(8))) short v8s;   // 8 bf16 in 4 VGPRs
typedef __attribute__((ext_vector_type(4))) float v4f;   // MFMA C/D frag

__device__ __forceinline__ bf16 tob(float x) { return __float2bfloat16(x); }

// async global->LDS, 16B per lane; LDS dest must be wave-uniform base + lane*16
__device__ __forceinline__ void gload16(const void* g, void* l) {
  __builtin_amdgcn_global_load_lds(
      (const __attribute__((address_space(1))) uint32_t*)g,
      (__attribute__((address_space(3))) uint32_t*)l,
      16, 0, 0);
}

// ============ fused input-only preprocessing (4 old kernels, 1 launch) ============
// blocks 0..511   : h1 = relu(fea @ W_l1 + b_l1)         (8,1024), K=1024
// blocks 512..767 : gp[b,n] = fea[b] @ W_c1[5:,n] + bc1  (8,512),  K=1024
// blocks 768..1023: W2T[n,k-swz] = bf16(W_c2[k,n])       (512,512) transpose
// block  1024     : G[g,k] = gx*Wc1[0,k] + gy*Wc1[1,k]   (16,512)
// All depend only on kernel inputs -> safe in one grid; branch is block-uniform.
__global__ void k_pre(const float* __restrict__ fea, const float* __restrict__ Wl1,
                      const float* __restrict__ bl1, const float* __restrict__ Wc1,
                      const float* __restrict__ bc1, const float* __restrict__ Wc2,
                      float* __restrict__ h1, float* __restrict__ gp,
                      bf16* __restrict__ WT, float* __restrict__ G) {
  __shared__ __align__(16) float sm[32 * 33 + 32];
  const int bid = blockIdx.x;
  if (bid < 512) {                     // ---- lin1 ----
    float* red = sm;
    const int nl = threadIdx.x & 15, ks = threadIdx.x >> 4;
    const int o = bid * 16 + nl;
    const int b = o >> 10, n = o & 1023;
    const float* fr = fea + (b << 10) + ks * 64;
    const float* wp = Wl1 + (size_t)(ks * 64) * 1024 + n;
    float acc = 0.f;
#pragma unroll 8
    for (int j = 0; j < 64; ++j)
      acc = fmaf(fr[j], wp[(size_t)j * 1024], acc);
    red[threadIdx.x] = acc;
    __syncthreads();
    if (threadIdx.x < 16) {
      float s = bl1[n];
#pragma unroll
      for (int i = 0; i < 16; ++i) s += red[i * 16 + threadIdx.x];
      h1[o] = fmaxf(s, 0.f);
    }
  } else if (bid < 768) {              // ---- gp ----
    float* red = sm;
    const int nl = threadIdx.x & 15, ks = threadIdx.x >> 4;
    const int o = (bid - 512) * 16 + nl;
    const int b = o >> 9, n = o & 511;
    const float* fr = fea + (b << 10) + ks * 64;
    const float* wp = Wc1 + (size_t)(5 + ks * 64) * 512 + n;
    float acc = 0.f;
#pragma unroll 8
    for (int j = 0; j < 64; ++j)
      acc = fmaf(fr[j], wp[(size_t)j * 512], acc);
    red[threadIdx.x] = acc;
    __syncthreads();
    if (threadIdx.x < 16) {
      float s = bc1[n];
#pragma unroll
      for (int i = 0; i < 16; ++i) s += red[i * 16 + threadIdx.x];
      gp[o] = s;
    }
  } else if (bid < 1024) {             // ---- w2t (pre-swizzled transpose) ----
    float (*tile)[33] = (float(*)[33])sm;
    const int bb = bid - 768;
    int bx = bb & 15, by = bb >> 4;
    int c = threadIdx.x & 31, r8 = threadIdx.x >> 5;
#pragma unroll
    for (int i = 0; i < 4; ++i) {
      int r = r8 + i * 8;
      tile[r][c] = Wc2[(by * 32 + r) * 512 + bx * 32 + c];
    }
    __syncthreads();
#pragma unroll
    for (int i = 0; i < 4; ++i) {
      int r = r8 + i * 8;
      int n = bx * 32 + r;                       // output row (conv2 in-chan)
      int k = by * 32 + c;                       // original k
      int s = (c >> 3) & 3;                      // 16B slot in 64B K-block
      int ks = (k & ~24) | (((s ^ ((n >> 1) & 3)) & 3) << 3);
      WT[(size_t)n * 512 + ks] = tob(tile[c][r]);
    }
  } else {                             // ---- grid table ----
    for (int e = threadIdx.x; e < 8192; e += 256) {
      int g = e >> 9, k = e & 511;
      const float gx = -0.05f + (float)(g & 3) * (0.1f / 3.0f);
      const float gy = -0.05f + (float)(g >> 2) * (0.1f / 3.0f);
      G[e] = fmaf(gy, Wc1[512 + k], gx * Wc1[k]);
    }
  }
}

// x = h1 @ W_l2 + b_l2   (8,3072), K=1024 -> xf (ws) + xout (d_out)
__global__ void k_lin2(const float* __restrict__ h1, const float* __restrict__ W,
                       const float* __restrict__ bias, float* __restrict__ xf,
                       float* __restrict__ xout) {
  __shared__ float red[256];
  const int nl = threadIdx.x & 15, ks = threadIdx.x >> 4;
  const int o = blockIdx.x * 16 + nl;            // 0..24575, same b within block
  const int b = o / 3072, n = o - b * 3072;
  const float* hr = h1 + (b << 10) + ks * 64;
  const float* wp = W + (size_t)(ks * 64) * 3072 + n;
  float acc = 0.f;
#pragma unroll 8
  for (int j = 0; j < 64; ++j)
    acc = fmaf(hr[j], wp[(size_t)j * 3072], acc);
  red[threadIdx.x] = acc;
  __syncthreads();
  if (threadIdx.x < 16) {
    float s = bias[n];
#pragma unroll
    for (int i = 0; i < 16; ++i) s += red[i * 16 + threadIdx.x];
    xf[o] = s;
    xout[o] = s;
  }
}

// P[b*1024+c, k] = gp[b,k] + x0*Wc1[2,k] + x1*Wc1[3,k] + x2*Wc1[4,k]
// (8192,512) f32, 16 MB. Hoists the per-coarse-point part of the conv1 input
// out of k_gemm's inner loop.
__global__ void k_pp(const float* __restrict__ gp, const float* __restrict__ xf,
                     const float* __restrict__ Wc1, float* __restrict__ P) {
  const int t = threadIdx.x;                    // 512
  const int row = blockIdx.x * 4 + (t >> 7);    // (b,c), 2048 blocks
  const int k4 = (t & 127) << 2;
  const int b = row >> 10;
  const float* xp = xf + row * 3;
  const float x0 = xp[0], x1 = xp[1], x2 = xp[2];
  float4 gv = *(const float4*)(gp + (b << 9) + k4);
  float4 w2 = *(const float4*)(Wc1 + 2 * 512 + k4);
  float4 w3 = *(const float4*)(Wc1 + 3 * 512 + k4);
  float4 w4 = *(const float4*)(Wc1 + 4 * 512 + k4);
  float4 r;
  r.x = fmaf(x2, w4.x, fmaf(x1, w3.x, fmaf(x0, w2.x, gv.x)));
  r.y = fmaf(x2, w4.y, fmaf(x1, w3.y, fmaf(x0, w2.y, gv.y)));
  r.z = fmaf(x2, w4.z, fmaf(x1, w3.z, fmaf(x0, w2.z, gv.z)));
  r.w = fmaf(x2, w4.w, fmaf(x1, w3.w, fmaf(x0, w2.w, gv.w)));
  *(float4*)(P + (size_t)row * 512 + k4) = r;
}

// ============ fused conv1+conv2 GEMM + conv3 epilogue ============
// 2048 blocks x 512 threads. Block: rows m0..m0+127, N-half nblk*256..+255,
// K=512, BK=32. LDS = 50688 B; 3x50688 = 152 KB <= 160 KB, so with VGPR <= 85
// ((512,6)) the CU hosts 3 blocks (24 waves) -> inter-block overlap hides the
// per-kt barrier drain. Round-3 natural VGPR was 56 (+16 prefetch ~= 72 < 85:
// spill-free; round-1's spill disaster was at 104 natural vs 85 cap).
// T14 async-STAGE split: P/G for tile kt+1 are prefetched into registers one
// iteration early, so the post-barrier stage is pure VALU+ds_write -- the
// ~300cy L2 load latency no longer sits inside the barrier-drain window.
// B staged via gload16 from pre-swizzled W2T; A write/read swizzle the 16B
// k-slot by (row>>1)&3 (bank-conflict-free, verified 0). conv3 partials
// (N split in 2) -> global atomicAdd onto memset fine.
__global__ __launch_bounds__(512, 6)
void k_gemm(const bf16* __restrict__ W2T, const float* __restrict__ P,
            const float* __restrict__ G, const float* __restrict__ xf,
            const float* __restrict__ bc2, const float* __restrict__ Wc3,
            const float* __restrict__ bc3, float* __restrict__ fine) {
  __shared__ __align__(16) bf16 As[2][128 * 32];   // 2 x 8 KB
  __shared__ __align__(16) bf16 Bs[2][256 * 32];   // 2 x 16 KB
  __shared__ float facc[128][3];                   // 1.5 KB
  const int t = threadIdx.x;
  const int mblk = blockIdx.x >> 1, nblk = blockIdx.x & 1;
  const int m0 = mblk * 128;
  const int w = t >> 6, l = t & 63, q = l >> 4, lm = l & 15;
  const int wm = (w >> 2) * 64;          // wave output-row base (0 or 64)
  const int wn = (w & 3) * 64;           // wave output-col base within N-half
  const int qs = (q ^ ((lm >> 1) & 3)) << 4;  // swizzled 16B slot for frag reads

  if (t < 384) ((float*)facc)[t] = 0.f;

  // ---- A-compute role: thread -> (row arow, k-subgroup cg of 8) ----
  const int arow = t >> 2, cg = t & 3;
  const int m = m0 + arow;
  const int b = m >> 14;                 // batch, uniform per block
  const int f = m & 16383;
  const int c = f >> 4, g = f & 15;
  const float* pr = P + ((size_t)(b * 1024 + c) << 9);  // P row (512 f32)
  const float* gr = G + (g << 9);                       // G row (512 f32)
  char* awr = (char*)As + arow * 64 + ((cg ^ ((arow >> 1) & 3)) << 4); // + buf*8192

  // ---- B staging role: wave stages rows [w*32, w*32+32), 2 gload16/thread ----
  const char* bsrc = (const char*)W2T +
      (size_t)(nblk * 256 + w * 32 + (l >> 2)) * 1024 + (l & 3) * 16;
  char* bdst = (char*)Bs + w * 2048 + l * 16;      // + buf*16384 + i*1024

  v4f acc[4][4];
#pragma unroll
  for (int mi = 0; mi < 4; ++mi)
#pragma unroll
    for (int ni = 0; ni < 4; ++ni) acc[mi][ni] = (v4f){0.f, 0.f, 0.f, 0.f};

  // T14 prefetch registers: P/G values for the NEXT tile to be staged
  float4 pf0, pf1, gf0, gf1;
  auto loadPG = [&](int kt) {
    const int kk = kt * 32 + cg * 8;
    pf0 = *(const float4*)(pr + kk);
    pf1 = *(const float4*)(pr + kk + 4);
    gf0 = *(const float4*)(gr + kk);
    gf1 = *(const float4*)(gr + kk + 4);
  };
  auto stage = [&](int kt, int buf) {
    // B: async loads in flight first
    const char* src = bsrc + kt * 64;
    char* dst = bdst + buf * 16384;
    gload16(src, dst);
    gload16(src + 16384, dst + 1024);    // +16 rows
    // A: relu(P+G) from PREFETCHED registers -> pure VALU + 16B ds_write
    union { bf16 h[8]; uint4 u; } o;
#pragma unroll
    for (int j = 0; j < 4; ++j) {
      o.h[j]     = tob(fmaxf(((const float*)&pf0)[j] + ((const float*)&gf0)[j], 0.f));
      o.h[4 + j] = tob(fmaxf(((const float*)&pf1)[j] + ((const float*)&gf1)[j], 0.f));
    }
    *(uint4*)(awr + buf * 8192) = o.u;
  };

  loadPG(0);
  stage(0, 0);
  loadPG(1);           // in flight across the first barrier + MFMA phase

#pragma unroll 2
  for (int kt = 0; kt < 16; ++kt) {
    const int buf = kt & 1;
    __syncthreads();                     // stage(kt,buf) complete on all waves
    if (kt < 15) {
      stage(kt + 1, buf ^ 1);            // consumes prefetched P/G(kt+1)
      if (kt < 14) loadPG(kt + 2);       // issue next prefetch; hides under MFMAs
    }
    const char* ab = (const char*)As + buf * 8192;
    const char* bb = (const char*)Bs + buf * 16384;
    v8s af[4], bfr[4];
#pragma unroll
    for (int mi = 0; mi < 4; ++mi)
      af[mi] = *(const v8s*)(ab + (wm + mi * 16 + lm) * 64 + qs);
#pragma unroll
    for (int ni = 0; ni < 4; ++ni)
      bfr[ni] = *(const v8s*)(bb + (wn + ni * 16 + lm) * 64 + qs);
#pragma unroll
    for (int mi = 0; mi < 4; ++mi)
#pragma unroll
      for (int ni = 0; ni < 4; ++ni)
        acc[mi][ni] = __builtin_amdgcn_mfma_f32_16x16x32_bf16(af[mi], bfr[ni], acc[mi][ni], 0, 0, 0);
  }

  // ---- epilogue: h2 = relu(acc + b_c2); fine partials via Wc3 ----
  float part[4][4][3];
#pragma unroll
  for (int mi = 0; mi < 4; ++mi)
#pragma unroll
    for (int r = 0; r < 4; ++r) { part[mi][r][0] = 0.f; part[mi][r][1] = 0.f; part[mi][r][2] = 0.f; }
#pragma unroll
  for (int ni = 0; ni < 4; ++ni) {
    const int n = nblk * 256 + wn + ni * 16 + lm;
    const float bv = bc2[n];
    const float w30 = Wc3[n * 3 + 0];
    const float w31 = Wc3[n * 3 + 1];
    const float w32 = Wc3[n * 3 + 2];
#pragma unroll
    for (int mi = 0; mi < 4; ++mi)
#pragma unroll
      for (int r = 0; r < 4; ++r) {
        float v = fmaxf(acc[mi][ni][r] + bv, 0.f);
        part[mi][r][0] = fmaf(v, w30, part[mi][r][0]);
        part[mi][r][1] = fmaf(v, w31, part[mi][r][1]);
        part[mi][r][2] = fmaf(v, w32, part[mi][r][2]);
      }
  }
#pragma unroll
  for (int mi = 0; mi < 4; ++mi)
#pragma unroll
    for (int r = 0; r < 4; ++r)
#pragma unroll
      for (int j = 0; j < 3; ++j) {
        float v = part[mi][r][j];
        v += __shfl_xor(v, 1);
        v += __shfl_xor(v, 2);
        v += __shfl_xor(v, 4);
        v += __shfl_xor(v, 8);
        if (lm == 0) atomicAdd(&facc[wm + mi * 16 + q * 4 + r][j], v);
      }
  __syncthreads();
  if (t < 128) {
    const int mm = m0 + t;
    float* fp = fine + (size_t)mm * 3;
    float base[3] = {0.f, 0.f, 0.f};
    if (nblk == 0) {
      const int bb2 = mm >> 14, cc = (mm & 16383) >> 4;
      const float* xq = xf + (bb2 * 1024 + cc) * 3;
#pragma unroll
      for (int j = 0; j < 3; ++j) base[j] = bc3[j] + xq[j];
    }
#pragma unroll
    for (int j = 0; j < 3; ++j)
      atomicAdd(&fp[j], facc[t][j] + base[j]);
  }
}

extern "C" void kernel_launch(void* const* d_in, const int* in_sizes, int n_in,
                              void* d_out, int out_size, void* d_ws, size_t ws_size,
                              hipStream_t stream) {
  const float* fea = (const float*)d_in[0];
  const float* Wl1 = (const float*)d_in[1];
  const float* bl1 = (const float*)d_in[2];
  const float* Wl2 = (const float*)d_in[3];
  const float* bl2 = (const float*)d_in[4];
  const float* Wc1 = (const float*)d_in[5];
  const float* bc1 = (const float*)d_in[6];
  const float* Wc2 = (const float*)d_in[7];
  const float* bc2 = (const float*)d_in[8];
  const float* Wc3 = (const float*)d_in[9];
  const float* bc3 = (const float*)d_in[10];
  float* xout = (float*)d_out;                // (8,1024,3)
  float* fine = (float*)d_out + 24576;        // (8,16384,3)
  char* ws = (char*)d_ws;
  float* h1  = (float*)ws;                    // 32 KB
  float* xf  = (float*)(ws + 32768);          // 96 KB
  float* gp  = (float*)(ws + 131072);         // 16 KB
  bf16*  W2T = (bf16*)(ws + 147456);          // 512 KB
  float* G   = (float*)(ws + 671744);         // 32 KB
  float* P   = (float*)(ws + 704512);         // 16 MB

  hipMemsetAsync(fine, 0, (size_t)131072 * 3 * sizeof(float), stream);
  k_pre<<<1025, 256, 0, stream>>>(fea, Wl1, bl1, Wc1, bc1, Wc2, h1, gp, W2T, G);
  k_lin2<<<1536, 256, 0, stream>>>(h1, Wl2, bl2, xf, xout);
  k_pp<<<2048, 512, 0, stream>>>(gp, xf, Wc1, P);
  k_gemm<<<2048, 512, 0, stream>>>(W2T, P, G, xf, bc2, Wc3, bc3, fine);
}

// Round 5
// 229.707 us; speedup vs baseline: 3.3852x; 3.3852x over previous
//
#include <hip/hip_runtime.h>
#include <hip/hip_bf16.h>
#include <stdint.h>

typedef __hip_bfloat16 bf16;
typedef __attribute__((ext_vector_type(8))) short v8s;   // 8 bf16 in 4 VGPRs
typedef __attribute__((ext_vector_type(4))) float v4f;   // MFMA C/D frag

__device__ __forceinline__ bf16 tob(float x) { return __float2bfloat16(x); }

// async global->LDS, 16B per lane; LDS dest must be wave-uniform base + lane*16
__device__ __forceinline__ void gload16(const void* g, void* l) {
  __builtin_amdgcn_global_load_lds(
      (const __attribute__((address_space(1))) uint32_t*)g,
      (__attribute__((address_space(3))) uint32_t*)l,
      16, 0, 0);
}

// ============ fused input-only preprocessing (4 old kernels, 1 launch) ============
// blocks 0..511   : h1 = relu(fea @ W_l1 + b_l1)         (8,1024), K=1024
// blocks 512..767 : gp[b,n] = fea[b] @ W_c1[5:,n] + bc1  (8,512),  K=1024
// blocks 768..1023: W2T[n,k-swz] = bf16(W_c2[k,n])       (512,512) transpose
// block  1024     : G[g,k] = gx*Wc1[0,k] + gy*Wc1[1,k]   (16,512)
// All depend only on kernel inputs -> safe in one grid; branch is block-uniform.
__global__ void k_pre(const float* __restrict__ fea, const float* __restrict__ Wl1,
                      const float* __restrict__ bl1, const float* __restrict__ Wc1,
                      const float* __restrict__ bc1, const float* __restrict__ Wc2,
                      float* __restrict__ h1, float* __restrict__ gp,
                      bf16* __restrict__ WT, float* __restrict__ G) {
  __shared__ __align__(16) float sm[32 * 33 + 32];
  const int bid = blockIdx.x;
  if (bid < 512) {                     // ---- lin1 ----
    float* red = sm;
    const int nl = threadIdx.x & 15, ks = threadIdx.x >> 4;
    const int o = bid * 16 + nl;
    const int b = o >> 10, n = o & 1023;
    const float* fr = fea + (b << 10) + ks * 64;
    const float* wp = Wl1 + (size_t)(ks * 64) * 1024 + n;
    float acc = 0.f;
#pragma unroll 8
    for (int j = 0; j < 64; ++j)
      acc = fmaf(fr[j], wp[(size_t)j * 1024], acc);
    red[threadIdx.x] = acc;
    __syncthreads();
    if (threadIdx.x < 16) {
      float s = bl1[n];
#pragma unroll
      for (int i = 0; i < 16; ++i) s += red[i * 16 + threadIdx.x];
      h1[o] = fmaxf(s, 0.f);
    }
  } else if (bid < 768) {              // ---- gp ----
    float* red = sm;
    const int nl = threadIdx.x & 15, ks = threadIdx.x >> 4;
    const int o = (bid - 512) * 16 + nl;
    const int b = o >> 9, n = o & 511;
    const float* fr = fea + (b << 10) + ks * 64;
    const float* wp = Wc1 + (size_t)(5 + ks * 64) * 512 + n;
    float acc = 0.f;
#pragma unroll 8
    for (int j = 0; j < 64; ++j)
      acc = fmaf(fr[j], wp[(size_t)j * 512], acc);
    red[threadIdx.x] = acc;
    __syncthreads();
    if (threadIdx.x < 16) {
      float s = bc1[n];
#pragma unroll
      for (int i = 0; i < 16; ++i) s += red[i * 16 + threadIdx.x];
      gp[o] = s;
    }
  } else if (bid < 1024) {             // ---- w2t (pre-swizzled transpose) ----
    float (*tile)[33] = (float(*)[33])sm;
    const int bb = bid - 768;
    int bx = bb & 15, by = bb >> 4;
    int c = threadIdx.x & 31, r8 = threadIdx.x >> 5;
#pragma unroll
    for (int i = 0; i < 4; ++i) {
      int r = r8 + i * 8;
      tile[r][c] = Wc2[(by * 32 + r) * 512 + bx * 32 + c];
    }
    __syncthreads();
#pragma unroll
    for (int i = 0; i < 4; ++i) {
      int r = r8 + i * 8;
      int n = bx * 32 + r;                       // output row (conv2 in-chan)
      int k = by * 32 + c;                       // original k
      int s = (c >> 3) & 3;                      // 16B slot in 64B K-block
      int ks = (k & ~24) | (((s ^ ((n >> 1) & 3)) & 3) << 3);
      WT[(size_t)n * 512 + ks] = tob(tile[c][r]);
    }
  } else {                             // ---- grid table ----
    for (int e = threadIdx.x; e < 8192; e += 256) {
      int g = e >> 9, k = e & 511;
      const float gx = -0.05f + (float)(g & 3) * (0.1f / 3.0f);
      const float gy = -0.05f + (float)(g >> 2) * (0.1f / 3.0f);
      G[e] = fmaf(gy, Wc1[512 + k], gx * Wc1[k]);
    }
  }
}

// x = h1 @ W_l2 + b_l2   (8,3072), K=1024 -> xf (ws) + xout (d_out)
__global__ void k_lin2(const float* __restrict__ h1, const float* __restrict__ W,
                       const float* __restrict__ bias, float* __restrict__ xf,
                       float* __restrict__ xout) {
  __shared__ float red[256];
  const int nl = threadIdx.x & 15, ks = threadIdx.x >> 4;
  const int o = blockIdx.x * 16 + nl;            // 0..24575, same b within block
  const int b = o / 3072, n = o - b * 3072;
  const float* hr = h1 + (b << 10) + ks * 64;
  const float* wp = W + (size_t)(ks * 64) * 3072 + n;
  float acc = 0.f;
#pragma unroll 8
  for (int j = 0; j < 64; ++j)
    acc = fmaf(hr[j], wp[(size_t)j * 3072], acc);
  red[threadIdx.x] = acc;
  __syncthreads();
  if (threadIdx.x < 16) {
    float s = bias[n];
#pragma unroll
    for (int i = 0; i < 16; ++i) s += red[i * 16 + threadIdx.x];
    xf[o] = s;
    xout[o] = s;
  }
}

// P[b*1024+c, k] = gp[b,k] + x0*Wc1[2,k] + x1*Wc1[3,k] + x2*Wc1[4,k]
// (8192,512) f32, 16 MB. Hoists the per-coarse-point part of the conv1 input
// out of k_gemm's inner loop.
__global__ void k_pp(const float* __restrict__ gp, const float* __restrict__ xf,
                     const float* __restrict__ Wc1, float* __restrict__ P) {
  const int t = threadIdx.x;                    // 512
  const int row = blockIdx.x * 4 + (t >> 7);    // (b,c), 2048 blocks
  const int k4 = (t & 127) << 2;
  const int b = row >> 10;
  const float* xp = xf + row * 3;
  const float x0 = xp[0], x1 = xp[1], x2 = xp[2];
  float4 gv = *(const float4*)(gp + (b << 9) + k4);
  float4 w2 = *(const float4*)(Wc1 + 2 * 512 + k4);
  float4 w3 = *(const float4*)(Wc1 + 3 * 512 + k4);
  float4 w4 = *(const float4*)(Wc1 + 4 * 512 + k4);
  float4 r;
  r.x = fmaf(x2, w4.x, fmaf(x1, w3.x, fmaf(x0, w2.x, gv.x)));
  r.y = fmaf(x2, w4.y, fmaf(x1, w3.y, fmaf(x0, w2.y, gv.y)));
  r.z = fmaf(x2, w4.z, fmaf(x1, w3.z, fmaf(x0, w2.z, gv.z)));
  r.w = fmaf(x2, w4.w, fmaf(x1, w3.w, fmaf(x0, w2.w, gv.w)));
  *(float4*)(P + (size_t)row * 512 + k4) = r;
}

// ============ fused conv1+conv2 GEMM + conv3 epilogue ============
// 2048 blocks x 512 threads. Block: rows m0..m0+127, N-half nblk*256..+255,
// K=512, BK=32. LDS = 50688 B, 2 blocks/CU (16 waves) -- one block's barrier
// drain overlaps the sibling's MFMAs (m114 overlap).
// LAUNCH-BOUNDS RULE (measured twice): (512,6) caps VGPR at 85 < real demand
// (~104+16 prefetch) -> accumulator spills to scratch -> GBs of HBM traffic,
// 677-872 us (rounds 1 & 4). (512,4) caps at 128: spill-free. DO NOT RAISE.
// T14 async-STAGE split: P/G for tile kt+1 are prefetched into registers one
// iteration early, so the post-barrier stage is pure VALU+ds_write -- the
// ~300cy L2 load latency hides under the previous kt's frag reads + MFMAs.
// B staged via gload16 from pre-swizzled W2T; A write/read swizzle the 16B
// k-slot by (row>>1)&3 (bank-conflict-free, verified 0). conv3 partials
// (N split in 2) -> global atomicAdd onto memset fine.
__global__ __launch_bounds__(512, 4)
void k_gemm(const bf16* __restrict__ W2T, const float* __restrict__ P,
            const float* __restrict__ G, const float* __restrict__ xf,
            const float* __restrict__ bc2, const float* __restrict__ Wc3,
            const float* __restrict__ bc3, float* __restrict__ fine) {
  __shared__ __align__(16) bf16 As[2][128 * 32];   // 2 x 8 KB
  __shared__ __align__(16) bf16 Bs[2][256 * 32];   // 2 x 16 KB
  __shared__ float facc[128][3];                   // 1.5 KB
  const int t = threadIdx.x;
  const int mblk = blockIdx.x >> 1, nblk = blockIdx.x & 1;
  const int m0 = mblk * 128;
  const int w = t >> 6, l = t & 63, q = l >> 4, lm = l & 15;
  const int wm = (w >> 2) * 64;          // wave output-row base (0 or 64)
  const int wn = (w & 3) * 64;           // wave output-col base within N-half
  const int qs = (q ^ ((lm >> 1) & 3)) << 4;  // swizzled 16B slot for frag reads

  if (t < 384) ((float*)facc)[t] = 0.f;

  // ---- A-compute role: thread -> (row arow, k-subgroup cg of 8) ----
  const int arow = t >> 2, cg = t & 3;
  const int m = m0 + arow;
  const int b = m >> 14;                 // batch, uniform per block
  const int f = m & 16383;
  const int c = f >> 4, g = f & 15;
  const float* pr = P + ((size_t)(b * 1024 + c) << 9);  // P row (512 f32)
  const float* gr = G + (g << 9);                       // G row (512 f32)
  char* awr = (char*)As + arow * 64 + ((cg ^ ((arow >> 1) & 3)) << 4); // + buf*8192

  // ---- B staging role: wave stages rows [w*32, w*32+32), 2 gload16/thread ----
  const char* bsrc = (const char*)W2T +
      (size_t)(nblk * 256 + w * 32 + (l >> 2)) * 1024 + (l & 3) * 16;
  char* bdst = (char*)Bs + w * 2048 + l * 16;      // + buf*16384 + i*1024

  v4f acc[4][4];
#pragma unroll
  for (int mi = 0; mi < 4; ++mi)
#pragma unroll
    for (int ni = 0; ni < 4; ++ni) acc[mi][ni] = (v4f){0.f, 0.f, 0.f, 0.f};

  // T14 prefetch registers: P/G values for the NEXT tile to be staged
  float4 pf0, pf1, gf0, gf1;
  auto loadPG = [&](int kt) {
    const int kk = kt * 32 + cg * 8;
    pf0 = *(const float4*)(pr + kk);
    pf1 = *(const float4*)(pr + kk + 4);
    gf0 = *(const float4*)(gr + kk);
    gf1 = *(const float4*)(gr + kk + 4);
  };
  auto stage = [&](int kt, int buf) {
    // B: async loads in flight first
    const char* src = bsrc + kt * 64;
    char* dst = bdst + buf * 16384;
    gload16(src, dst);
    gload16(src + 16384, dst + 1024);    // +16 rows
    // A: relu(P+G) from PREFETCHED registers -> pure VALU + 16B ds_write
    union { bf16 h[8]; uint4 u; } o;
#pragma unroll
    for (int j = 0; j < 4; ++j) {
      o.h[j]     = tob(fmaxf(((const float*)&pf0)[j] + ((const float*)&gf0)[j], 0.f));
      o.h[4 + j] = tob(fmaxf(((const float*)&pf1)[j] + ((const float*)&gf1)[j], 0.f));
    }
    *(uint4*)(awr + buf * 8192) = o.u;
  };

  loadPG(0);
  stage(0, 0);
  loadPG(1);           // in flight across the first barrier + MFMA phase

#pragma unroll 2
  for (int kt = 0; kt < 16; ++kt) {
    const int buf = kt & 1;
    __syncthreads();                     // stage(kt,buf) complete on all waves
    if (kt < 15) {
      stage(kt + 1, buf ^ 1);            // consumes prefetched P/G(kt+1)
      if (kt < 14) loadPG(kt + 2);       // issue next prefetch; hides under MFMAs
    }
    const char* ab = (const char*)As + buf * 8192;
    const char* bb = (const char*)Bs + buf * 16384;
    v8s af[4], bfr[4];
#pragma unroll
    for (int mi = 0; mi < 4; ++mi)
      af[mi] = *(const v8s*)(ab + (wm + mi * 16 + lm) * 64 + qs);
#pragma unroll
    for (int ni = 0; ni < 4; ++ni)
      bfr[ni] = *(const v8s*)(bb + (wn + ni * 16 + lm) * 64 + qs);
#pragma unroll
    for (int mi = 0; mi < 4; ++mi)
#pragma unroll
      for (int ni = 0; ni < 4; ++ni)
        acc[mi][ni] = __builtin_amdgcn_mfma_f32_16x16x32_bf16(af[mi], bfr[ni], acc[mi][ni], 0, 0, 0);
  }

  // ---- epilogue: h2 = relu(acc + b_c2); fine partials via Wc3 ----
  float part[4][4][3];
#pragma unroll
  for (int mi = 0; mi < 4; ++mi)
#pragma unroll
    for (int r = 0; r < 4; ++r) { part[mi][r][0] = 0.f; part[mi][r][1] = 0.f; part[mi][r][2] = 0.f; }
#pragma unroll
  for (int ni = 0; ni < 4; ++ni) {
    const int n = nblk * 256 + wn + ni * 16 + lm;
    const float bv = bc2[n];
    const float w30 = Wc3[n * 3 + 0];
    const float w31 = Wc3[n * 3 + 1];
    const float w32 = Wc3[n * 3 + 2];
#pragma unroll
    for (int mi = 0; mi < 4; ++mi)
#pragma unroll
      for (int r = 0; r < 4; ++r) {
        float v = fmaxf(acc[mi][ni][r] + bv, 0.f);
        part[mi][r][0] = fmaf(v, w30, part[mi][r][0]);
        part[mi][r][1] = fmaf(v, w31, part[mi][r][1]);
        part[mi][r][2] = fmaf(v, w32, part[mi][r][2]);
      }
  }
#pragma unroll
  for (int mi = 0; mi < 4; ++mi)
#pragma unroll
    for (int r = 0; r < 4; ++r)
#pragma unroll
      for (int j = 0; j < 3; ++j) {
        float v = part[mi][r][j];
        v += __shfl_xor(v, 1);
        v += __shfl_xor(v, 2);
        v += __shfl_xor(v, 4);
        v += __shfl_xor(v, 8);
        if (lm == 0) atomicAdd(&facc[wm + mi * 16 + q * 4 + r][j], v);
      }
  __syncthreads();
  if (t < 128) {
    const int mm = m0 + t;
    float* fp = fine + (size_t)mm * 3;
    float base[3] = {0.f, 0.f, 0.f};
    if (nblk == 0) {
      const int bb2 = mm >> 14, cc = (mm & 16383) >> 4;
      const float* xq = xf + (bb2 * 1024 + cc) * 3;
#pragma unroll
      for (int j = 0; j < 3; ++j) base[j] = bc3[j] + xq[j];
    }
#pragma unroll
    for (int j = 0; j < 3; ++j)
      atomicAdd(&fp[j], facc[t][j] + base[j]);
  }
}

extern "C" void kernel_launch(void* const* d_in, const int* in_sizes, int n_in,
                              void* d_out, int out_size, void* d_ws, size_t ws_size,
                              hipStream_t stream) {
  const float* fea = (const float*)d_in[0];
  const float* Wl1 = (const float*)d_in[1];
  const float* bl1 = (const float*)d_in[2];
  const float* Wl2 = (const float*)d_in[3];
  const float* bl2 = (const float*)d_in[4];
  const float* Wc1 = (const float*)d_in[5];
  const float* bc1 = (const float*)d_in[6];
  const float* Wc2 = (const float*)d_in[7];
  const float* bc2 = (const float*)d_in[8];
  const float* Wc3 = (const float*)d_in[9];
  const float* bc3 = (const float*)d_in[10];
  float* xout = (float*)d_out;                // (8,1024,3)
  float* fine = (float*)d_out + 24576;        // (8,16384,3)
  char* ws = (char*)d_ws;
  float* h1  = (float*)ws;                    // 32 KB
  float* xf  = (float*)(ws + 32768);          // 96 KB
  float* gp  = (float*)(ws + 131072);         // 16 KB
  bf16*  W2T = (bf16*)(ws + 147456);          // 512 KB
  float* G   = (float*)(ws + 671744);         // 32 KB
  float* P   = (float*)(ws + 704512);         // 16 MB

  hipMemsetAsync(fine, 0, (size_t)131072 * 3 * sizeof(float), stream);
  k_pre<<<1025, 256, 0, stream>>>(fea, Wl1, bl1, Wc1, bc1, Wc2, h1, gp, W2T, G);
  k_lin2<<<1536, 256, 0, stream>>>(h1, Wl2, bl2, xf, xout);
  k_pp<<<2048, 512, 0, stream>>>(gp, xf, Wc1, P);
  k_gemm<<<2048, 512, 0, stream>>>(W2T, P, G, xf, bc2, Wc3, bc3, fine);
}

// Round 6
// 182.077 us; speedup vs baseline: 4.2707x; 1.2616x over previous
//
#include <hip/hip_runtime.h>
#include <hip/hip_bf16.h>
#include <stdint.h>

typedef __hip_bfloat16 bf16;
typedef __attribute__((ext_vector_type(8))) short v8s;   // 8 bf16 in 4 VGPRs
typedef __attribute__((ext_vector_type(4))) float v4f;   // MFMA C/D frag

__device__ __forceinline__ bf16 tob(float x) { return __float2bfloat16(x); }

// async global->LDS, 16B per lane; LDS dest must be wave-uniform base + lane*16
__device__ __forceinline__ void gload16(const void* g, void* l) {
  __builtin_amdgcn_global_load_lds(
      (const __attribute__((address_space(1))) uint32_t*)g,
      (__attribute__((address_space(3))) uint32_t*)l,
      16, 0, 0);
}

// Sum over each aligned 16-lane group via DPP (VALU pipe, no LDS crossbar).
// quad_perm xor1, quad_perm xor2, row_half_mirror, row_mirror covers all 16.
__device__ __forceinline__ float red16(float v) {
  v += __int_as_float(__builtin_amdgcn_update_dpp(0, __float_as_int(v), 0xB1, 0xF, 0xF, true));
  v += __int_as_float(__builtin_amdgcn_update_dpp(0, __float_as_int(v), 0x4E, 0xF, 0xF, true));
  v += __int_as_float(__builtin_amdgcn_update_dpp(0, __float_as_int(v), 0x141, 0xF, 0xF, true));
  v += __int_as_float(__builtin_amdgcn_update_dpp(0, __float_as_int(v), 0x140, 0xF, 0xF, true));
  return v;
}

// ============ fused input-only preprocessing (1 launch) ============
// blocks 0..511   : h1 = relu(fea @ W_l1 + b_l1)         (8,1024), K=1024
// blocks 512..767 : gp[b,n] = fea[b] @ W_c1[5:,n] + bc1  (8,512),  K=1024
// blocks 768..1023: W2T[n,k-swz] = bf16(W_c2[k,n])       (512,512) transpose
// block  1024     : G[g,k] = gx*Wc1[0,k] + gy*Wc1[1,k]   (16,512)
__global__ void k_pre(const float* __restrict__ fea, const float* __restrict__ Wl1,
                      const float* __restrict__ bl1, const float* __restrict__ Wc1,
                      const float* __restrict__ bc1, const float* __restrict__ Wc2,
                      float* __restrict__ h1, float* __restrict__ gp,
                      bf16* __restrict__ WT, float* __restrict__ G) {
  __shared__ __align__(16) float sm[32 * 33 + 32];
  const int bid = blockIdx.x;
  if (bid < 512) {                     // ---- lin1 ----
    float* red = sm;
    const int nl = threadIdx.x & 15, ks = threadIdx.x >> 4;
    const int o = bid * 16 + nl;
    const int b = o >> 10, n = o & 1023;
    const float* fr = fea + (b << 10) + ks * 64;
    const float* wp = Wl1 + (size_t)(ks * 64) * 1024 + n;
    float acc = 0.f;
#pragma unroll 8
    for (int j = 0; j < 64; ++j)
      acc = fmaf(fr[j], wp[(size_t)j * 1024], acc);
    red[threadIdx.x] = acc;
    __syncthreads();
    if (threadIdx.x < 16) {
      float s = bl1[n];
#pragma unroll
      for (int i = 0; i < 16; ++i) s += red[i * 16 + threadIdx.x];
      h1[o] = fmaxf(s, 0.f);
    }
  } else if (bid < 768) {              // ---- gp ----
    float* red = sm;
    const int nl = threadIdx.x & 15, ks = threadIdx.x >> 4;
    const int o = (bid - 512) * 16 + nl;
    const int b = o >> 9, n = o & 511;
    const float* fr = fea + (b << 10) + ks * 64;
    const float* wp = Wc1 + (size_t)(5 + ks * 64) * 512 + n;
    float acc = 0.f;
#pragma unroll 8
    for (int j = 0; j < 64; ++j)
      acc = fmaf(fr[j], wp[(size_t)j * 512], acc);
    red[threadIdx.x] = acc;
    __syncthreads();
    if (threadIdx.x < 16) {
      float s = bc1[n];
#pragma unroll
      for (int i = 0; i < 16; ++i) s += red[i * 16 + threadIdx.x];
      gp[o] = s;
    }
  } else if (bid < 1024) {             // ---- w2t (pre-swizzled transpose) ----
    float (*tile)[33] = (float(*)[33])sm;
    const int bb = bid - 768;
    int bx = bb & 15, by = bb >> 4;
    int c = threadIdx.x & 31, r8 = threadIdx.x >> 5;
#pragma unroll
    for (int i = 0; i < 4; ++i) {
      int r = r8 + i * 8;
      tile[r][c] = Wc2[(by * 32 + r) * 512 + bx * 32 + c];
    }
    __syncthreads();
#pragma unroll
    for (int i = 0; i < 4; ++i) {
      int r = r8 + i * 8;
      int n = bx * 32 + r;                       // output row (conv2 in-chan)
      int k = by * 32 + c;                       // original k
      int s = (c >> 3) & 3;                      // 16B slot in 64B K-block
      int ks = (k & ~24) | (((s ^ ((n >> 1) & 3)) & 3) << 3);
      WT[(size_t)n * 512 + ks] = tob(tile[c][r]);
    }
  } else {                             // ---- grid table ----
    for (int e = threadIdx.x; e < 8192; e += 256) {
      int g = e >> 9, k = e & 511;
      const float gx = -0.05f + (float)(g & 3) * (0.1f / 3.0f);
      const float gy = -0.05f + (float)(g >> 2) * (0.1f / 3.0f);
      G[e] = fmaf(gy, Wc1[512 + k], gx * Wc1[k]);
    }
  }
}

// x = h1 @ W_l2 + b_l2   (8,3072), K=1024 -> xf (ws) + xout (d_out)
__global__ void k_lin2(const float* __restrict__ h1, const float* __restrict__ W,
                       const float* __restrict__ bias, float* __restrict__ xf,
                       float* __restrict__ xout) {
  __shared__ float red[256];
  const int nl = threadIdx.x & 15, ks = threadIdx.x >> 4;
  const int o = blockIdx.x * 16 + nl;            // 0..24575, same b within block
  const int b = o / 3072, n = o - b * 3072;
  const float* hr = h1 + (b << 10) + ks * 64;
  const float* wp = W + (size_t)(ks * 64) * 3072 + n;
  float acc = 0.f;
#pragma unroll 8
  for (int j = 0; j < 64; ++j)
    acc = fmaf(hr[j], wp[(size_t)j * 3072], acc);
  red[threadIdx.x] = acc;
  __syncthreads();
  if (threadIdx.x < 16) {
    float s = bias[n];
#pragma unroll
    for (int i = 0; i < 16; ++i) s += red[i * 16 + threadIdx.x];
    xf[o] = s;
    xout[o] = s;
  }
}

// ============ fused conv1+conv2 GEMM + conv3 epilogue ============
// 2048 blocks x 512 threads. Block: rows m0..m0+127, N-half nblk*256..+255,
// K=512, BK=32. LDS = 67072 B -> 2 blocks/CU (16 waves), VGPR<=128 via (512,4).
// LAUNCH-BOUNDS RULE (measured twice): (512,6) caps VGPR at 85 < real demand
// -> accumulator spills -> GBs of scratch HBM traffic (rounds 1 & 4). KEEP 4.
// P (per-coarse-point conv1 partial, 8 rows x 512) is computed in a prologue
// into LDS: stage reads it via broadcast ds_read (no global P stream, no
// register prefetch -> no vmcnt(0) barrier poison, which is what made round-5's
// T14 null: the barrier's vmcnt(0) drained the kt+2 prefetches every kt).
// G (16x512, L2-hot) is loaded in-stage and consumed before the barrier.
// B staged via gload16 from pre-swizzled W2T; A write/read swizzle the 16B
// k-slot by (row>>1)&3 (bank-conflict-free, verified 0).
// Epilogue conv3: DPP 16-lane reduction (VALU pipe) instead of the shfl storm
// (was 192 ds_swizzle/thread ~= 3.1M crossbar ops kernel-wide).
__global__ __launch_bounds__(512, 4)
void k_gemm(const bf16* __restrict__ W2T, const float* __restrict__ gp,
            const float* __restrict__ G, const float* __restrict__ Wc1,
            const float* __restrict__ xf, const float* __restrict__ bc2,
            const float* __restrict__ Wc3, const float* __restrict__ bc3,
            float* __restrict__ fine) {
  __shared__ __align__(16) bf16 As[2][128 * 32];   // 2 x 8 KB
  __shared__ __align__(16) bf16 Bs[2][256 * 32];   // 2 x 16 KB
  __shared__ __align__(16) float Ps[8][512];       // 16 KB
  __shared__ float facc[128][3];                   // 1.5 KB
  const int t = threadIdx.x;
  const int mblk = blockIdx.x >> 1, nblk = blockIdx.x & 1;
  const int m0 = mblk * 128;
  const int w = t >> 6, l = t & 63, q = l >> 4, lm = l & 15;
  const int wm = (w >> 2) * 64;          // wave output-row base (0 or 64)
  const int wn = (w & 3) * 64;           // wave output-col base within N-half
  const int qs = (q ^ ((lm >> 1) & 3)) << 4;  // swizzled 16B slot for frag reads

  if (t < 384) ((float*)facc)[t] = 0.f;

  // ---- A-compute role: thread -> (row arow, k-subgroup cg of 8) ----
  const int arow = t >> 2, cg = t & 3;
  const int m = m0 + arow;
  const int b = m >> 14;                 // batch, uniform per block
  const int f = m & 16383;
  const int g = f & 15;
  const float* gr = G + (g << 9);                       // G row (512 f32)
  const float* pl = Ps[arow >> 4];                      // local P row in LDS
  char* awr = (char*)As + arow * 64 + ((cg ^ ((arow >> 1) & 3)) << 4); // + buf*8192

  // ---- P prologue: Ps[cl][k] = gp[b][k] + x·Wc1[2:5][k], 8 elems/thread ----
  {
    const int cl = t >> 6;               // local coarse point 0..7
    const int k8 = (t & 63) * 8;
    const int cglob = ((m0 & 16383) >> 4) + cl;
    const float* xq = xf + (b * 1024 + cglob) * 3;
    const float x0 = xq[0], x1 = xq[1], x2 = xq[2];
    const float* gpb = gp + (b << 9) + k8;
    float4 gv0 = *(const float4*)(gpb);
    float4 gv1 = *(const float4*)(gpb + 4);
    float4 w20 = *(const float4*)(Wc1 + 2 * 512 + k8);
    float4 w21 = *(const float4*)(Wc1 + 2 * 512 + k8 + 4);
    float4 w30 = *(const float4*)(Wc1 + 3 * 512 + k8);
    float4 w31 = *(const float4*)(Wc1 + 3 * 512 + k8 + 4);
    float4 w40 = *(const float4*)(Wc1 + 4 * 512 + k8);
    float4 w41 = *(const float4*)(Wc1 + 4 * 512 + k8 + 4);
    float4 r0, r1;
#pragma unroll
    for (int j = 0; j < 4; ++j) {
      ((float*)&r0)[j] = fmaf(x2, ((const float*)&w40)[j],
                         fmaf(x1, ((const float*)&w30)[j],
                         fmaf(x0, ((const float*)&w20)[j], ((const float*)&gv0)[j])));
      ((float*)&r1)[j] = fmaf(x2, ((const float*)&w41)[j],
                         fmaf(x1, ((const float*)&w31)[j],
                         fmaf(x0, ((const float*)&w21)[j], ((const float*)&gv1)[j])));
    }
    *(float4*)&Ps[cl][k8] = r0;
    *(float4*)&Ps[cl][k8 + 4] = r1;
  }

  // ---- B staging role: wave stages rows [w*32, w*32+32), 2 gload16/thread ----
  const char* bsrc = (const char*)W2T +
      (size_t)(nblk * 256 + w * 32 + (l >> 2)) * 1024 + (l & 3) * 16;
  char* bdst = (char*)Bs + w * 2048 + l * 16;      // + buf*16384 + i*1024

  v4f acc[4][4];
#pragma unroll
  for (int mi = 0; mi < 4; ++mi)
#pragma unroll
    for (int ni = 0; ni < 4; ++ni) acc[mi][ni] = (v4f){0.f, 0.f, 0.f, 0.f};

  auto stage = [&](int kt, int buf) {
    // B: async loads in flight first
    const char* src = bsrc + kt * 64;
    char* dst = bdst + buf * 16384;
    gload16(src, dst);
    gload16(src + 16384, dst + 1024);    // +16 rows
    // A: relu(P + G); P from LDS (broadcast ds_read), G from L2-hot global.
    const int kk = kt * 32 + cg * 8;
    float4 g0 = *(const float4*)(gr + kk);
    float4 g1 = *(const float4*)(gr + kk + 4);
    float4 p0 = *(const float4*)(pl + kk);
    float4 p1 = *(const float4*)(pl + kk + 4);
    union { bf16 h[8]; uint4 u; } o;
#pragma unroll
    for (int j = 0; j < 4; ++j) {
      o.h[j]     = tob(fmaxf(((const float*)&p0)[j] + ((const float*)&g0)[j], 0.f));
      o.h[4 + j] = tob(fmaxf(((const float*)&p1)[j] + ((const float*)&g1)[j], 0.f));
    }
    *(uint4*)(awr + buf * 8192) = o.u;
  };

  __syncthreads();                       // Ps visible to all waves
  stage(0, 0);

#pragma unroll 2
  for (int kt = 0; kt < 16; ++kt) {
    const int buf = kt & 1;
    __syncthreads();                     // stage(kt,buf) complete on all waves
    if (kt < 15) stage(kt + 1, buf ^ 1); // prefetch next tile (other buffer)
    const char* ab = (const char*)As + buf * 8192;
    const char* bb = (const char*)Bs + buf * 16384;
    v8s af[4], bfr[4];
#pragma unroll
    for (int mi = 0; mi < 4; ++mi)
      af[mi] = *(const v8s*)(ab + (wm + mi * 16 + lm) * 64 + qs);
#pragma unroll
    for (int ni = 0; ni < 4; ++ni)
      bfr[ni] = *(const v8s*)(bb + (wn + ni * 16 + lm) * 64 + qs);
#pragma unroll
    for (int mi = 0; mi < 4; ++mi)
#pragma unroll
      for (int ni = 0; ni < 4; ++ni)
        acc[mi][ni] = __builtin_amdgcn_mfma_f32_16x16x32_bf16(af[mi], bfr[ni], acc[mi][ni], 0, 0, 0);
  }

  // ---- epilogue: h2 = relu(acc + b_c2); fine partials via Wc3 ----
  float part[4][4][3];
#pragma unroll
  for (int mi = 0; mi < 4; ++mi)
#pragma unroll
    for (int r = 0; r < 4; ++r) { part[mi][r][0] = 0.f; part[mi][r][1] = 0.f; part[mi][r][2] = 0.f; }
#pragma unroll
  for (int ni = 0; ni < 4; ++ni) {
    const int n = nblk * 256 + wn + ni * 16 + lm;
    const float bv = bc2[n];
    const float w30 = Wc3[n * 3 + 0];
    const float w31 = Wc3[n * 3 + 1];
    const float w32 = Wc3[n * 3 + 2];
#pragma unroll
    for (int mi = 0; mi < 4; ++mi)
#pragma unroll
      for (int r = 0; r < 4; ++r) {
        float v = fmaxf(acc[mi][ni][r] + bv, 0.f);
        part[mi][r][0] = fmaf(v, w30, part[mi][r][0]);
        part[mi][r][1] = fmaf(v, w31, part[mi][r][1]);
        part[mi][r][2] = fmaf(v, w32, part[mi][r][2]);
      }
  }
#pragma unroll
  for (int mi = 0; mi < 4; ++mi)
#pragma unroll
    for (int r = 0; r < 4; ++r)
#pragma unroll
      for (int j = 0; j < 3; ++j) {
        float v = red16(part[mi][r][j]);   // DPP 16-lane sum (lm group)
        if (lm == 0) atomicAdd(&facc[wm + mi * 16 + q * 4 + r][j], v);
      }
  __syncthreads();
  if (t < 128) {
    const int mm = m0 + t;
    float* fp = fine + (size_t)mm * 3;
    float base[3] = {0.f, 0.f, 0.f};
    if (nblk == 0) {
      const int bb2 = mm >> 14, cc = (mm & 16383) >> 4;
      const float* xq = xf + (bb2 * 1024 + cc) * 3;
#pragma unroll
      for (int j = 0; j < 3; ++j) base[j] = bc3[j] + xq[j];
    }
#pragma unroll
    for (int j = 0; j < 3; ++j)
      atomicAdd(&fp[j], facc[t][j] + base[j]);
  }
}

extern "C" void kernel_launch(void* const* d_in, const int* in_sizes, int n_in,
                              void* d_out, int out_size, void* d_ws, size_t ws_size,
                              hipStream_t stream) {
  const float* fea = (const float*)d_in[0];
  const float* Wl1 = (const float*)d_in[1];
  const float* bl1 = (const float*)d_in[2];
  const float* Wl2 = (const float*)d_in[3];
  const float* bl2 = (const float*)d_in[4];
  const float* Wc1 = (const float*)d_in[5];
  const float* bc1 = (const float*)d_in[6];
  const float* Wc2 = (const float*)d_in[7];
  const float* bc2 = (const float*)d_in[8];
  const float* Wc3 = (const float*)d_in[9];
  const float* bc3 = (const float*)d_in[10];
  float* xout = (float*)d_out;                // (8,1024,3)
  float* fine = (float*)d_out + 24576;        // (8,16384,3)
  char* ws = (char*)d_ws;
  float* h1  = (float*)ws;                    // 32 KB
  float* xf  = (float*)(ws + 32768);          // 96 KB
  float* gp  = (float*)(ws + 131072);         // 16 KB
  bf16*  W2T = (bf16*)(ws + 147456);          // 512 KB
  float* G   = (float*)(ws + 671744);         // 32 KB

  hipMemsetAsync(fine, 0, (size_t)131072 * 3 * sizeof(float), stream);
  k_pre<<<1025, 256, 0, stream>>>(fea, Wl1, bl1, Wc1, bc1, Wc2, h1, gp, W2T, G);
  k_lin2<<<1536, 256, 0, stream>>>(h1, Wl2, bl2, xf, xout);
  k_gemm<<<2048, 512, 0, stream>>>(W2T, gp, G, Wc1, xf, bc2, Wc3, bc3, fine);
}